// Round 4
// baseline (10765.907 us; speedup 1.0000x reference)
//
#include <hip/hip_runtime.h>
#include <stdint.h>

#define BB 512
#define TT 256
#define FF 128
#define HH 256
#define NB 32          // blocks (16 rows each)
#define MR 16
#define EPSL 1e-9f

// ws bf16-element offsets. B-fragment-swizzled: [kt][nt][lane][8],
// elem (kt,nt,lane,j) holds B[k=kt*32+(lane>>4)*8+j][n=nt*16+(lane&15)]
#define E_WDH 0        // kt 4, nt 16  (gamma_h: K=128, N=256)
#define E_WH  32768    // kt 8, nt 8   (x_h:    K=256, N=128)
#define E_WF  65536    // kt 4, nt 8   (z_h:    K=128, N=128, diag zeroed)
#define E_WC  81920    // kt 8, nt 8   (alpha:  K=256, N=128)
#define E_W2  114688   // kt 16, nt 64 (gates:  K=512, N=1024)
#define E_END 638976
#define OFF_MSUM (E_END * 2)            // f32 [256]
#define OFF_PART (OFF_MSUM + 1024)      // f32 [3][TT][NB]

#define GPAD 1028      // g32 row stride (floats)

typedef __attribute__((ext_vector_type(8))) short s8v;   // 8 bf16
typedef __attribute__((ext_vector_type(4))) float f4v;   // 4 f32

__device__ __forceinline__ uint16_t f2bf(float v) {
    uint32_t u = __float_as_uint(v);
    return (uint16_t)((u + 0x7fffu + ((u >> 16) & 1u)) >> 16);  // RNE
}
__device__ __forceinline__ float fexp(float x) { return __expf(x); }
__device__ __forceinline__ float fsigm(float x) { return 1.f / (1.f + __expf(-x)); }
__device__ __forceinline__ float ftanh(float x) {
    float e = __expf(2.f * x);
    return 1.f - 2.f / (e + 1.f);
}
__device__ __forceinline__ uint32_t pack2(float a, float b) {
    return (uint32_t)f2bf(a) | ((uint32_t)f2bf(b) << 16);
}
// A-swizzled LDS index for element (k, m): lane=((k>>3)&3)*16+m, chunk j=k&7
__device__ __forceinline__ int aidx(int k, int m) {
    return ((k >> 5) << 9) + (((((k >> 3) & 3) << 4) + m) << 3) + (k & 7);
}

// ---------------- prep: pack weights into B-fragment bf16 layout ----------------
__global__ void prep_weights(const float* __restrict__ Wdh, const float* __restrict__ Wh,
                             const float* __restrict__ Wf, const float* __restrict__ Wc,
                             const float* __restrict__ Wih, const float* __restrict__ Whh,
                             uint16_t* __restrict__ wsu) {
    const int total = E_END;
    for (int i = blockIdx.x * blockDim.x + threadIdx.x; i < total; i += gridDim.x * blockDim.x) {
        float v;
        if (i < 32768) {                        // WdhB
            int o = i, j = o & 7, lane = (o >> 3) & 63, q = o >> 9;
            int nt = q & 15;
            int k = (q >> 4) * 32 + (lane >> 4) * 8 + j;
            int n = nt * 16 + (lane & 15);
            v = Wdh[n * 128 + k];
        } else if (i < 65536) {                 // WhB
            int o = i - 32768, j = o & 7, lane = (o >> 3) & 63, q = o >> 9;
            int nt = q & 7;
            int k = (q >> 3) * 32 + (lane >> 4) * 8 + j;
            int n = nt * 16 + (lane & 15);
            v = Wh[n * 256 + k];
        } else if (i < 81920) {                 // WfB (diag masked)
            int o = i - 65536, j = o & 7, lane = (o >> 3) & 63, q = o >> 9;
            int nt = q & 7;
            int k = (q >> 3) * 32 + (lane >> 4) * 8 + j;
            int n = nt * 16 + (lane & 15);
            v = (k == n) ? 0.f : Wf[n * 128 + k];
        } else if (i < 114688) {                // WcB
            int o = i - 81920, j = o & 7, lane = (o >> 3) & 63, q = o >> 9;
            int nt = q & 7;
            int k = (q >> 3) * 32 + (lane >> 4) * 8 + j;
            int n = nt * 16 + (lane & 15);
            v = Wc[n * 256 + k];
        } else {                                // W2B
            int o = i - 114688, j = o & 7, lane = (o >> 3) & 63, q = o >> 9;
            int nt = q & 63;
            int k = (q >> 6) * 32 + (lane >> 4) * 8 + j;
            int g = nt * 16 + (lane & 15);
            v = (k < 256) ? Wih[g * 256 + k] : Whh[g * 256 + (k - 256)];
        }
        wsu[i] = f2bf(v);
    }
}

// ---------------- msum[t] ----------------
__global__ void msum_kernel(const float* __restrict__ mask, float* __restrict__ msum) {
    int t = blockIdx.x;
    float s = 0.f;
    for (int i = threadIdx.x; i < BB * FF; i += 256) {
        int b = i >> 7, f = i & 127;
        s += mask[((long)b * TT + t) * FF + f];
    }
    __shared__ float red[4];
    for (int off = 32; off; off >>= 1) s += __shfl_down(s, off);
    if ((threadIdx.x & 63) == 0) red[threadIdx.x >> 6] = s;
    __syncthreads();
    if (threadIdx.x == 0) msum[t] = red[0] + red[1] + red[2] + red[3];
}

// ---------------- main: 32 blocks x 1024 threads (16 waves), 16 rows/block ----------------
__launch_bounds__(1024, 4)
__global__ void rits_main(const float* __restrict__ values, const float* __restrict__ mask,
                          const float* __restrict__ deltas,
                          const float* __restrict__ bdh, const float* __restrict__ Wdx,
                          const float* __restrict__ bdx, const float* __restrict__ bh,
                          const float* __restrict__ bf_, const float* __restrict__ bc_,
                          const float* __restrict__ bih, const float* __restrict__ bhh,
                          const uint16_t* __restrict__ wsu,
                          float* __restrict__ part, float* __restrict__ out_imp) {
    __shared__ __align__(16) uint16_t dA[4 * 512];     // d,  A-layout, K=128
    __shared__ __align__(16) uint16_t gxmA[8 * 512];   // [gx|m], K=256
    __shared__ __align__(16) uint16_t hA[8 * 512];     // decayed h, K=256
    __shared__ __align__(16) uint16_t xcA[4 * 512];    // x_c, K=128
    __shared__ __align__(16) uint16_t actA[16 * 512];  // [cc|m|h], K=512
    __shared__ __align__(16) float x32[16 * 132];
    __shared__ __align__(16) float m32[16 * 132];
    __shared__ __align__(16) float h32[16 * 264];
    __shared__ __align__(16) float al32[16 * 136];     // alpha exchange
    __shared__ __align__(16) float g32[16 * GPAD];     // gates interleaved [h*4+gate]
    __shared__ float wred[3][8];

    const int tid = threadIdx.x;
    const int blk = blockIdx.x;
    const int r0 = blk * MR;
    const int w = tid >> 6;        // wave 0..15
    const int L = tid & 63;        // lane
    const int col = L & 15;
    const int q = L >> 4;

    const s8v* WDHB = (const s8v*)(wsu + E_WDH);
    const s8v* WHB  = (const s8v*)(wsu + E_WH);
    const s8v* WFB  = (const s8v*)(wsu + E_WF);
    const s8v* WCB  = (const s8v*)(wsu + E_WC);
    const s8v* W2B  = (const s8v*)(wsu + E_W2);

    // ---- IN-phase mapping: row = w, two features per thread ----
    const int f2 = L * 2;
    const float cwdx0 = Wdx[f2 * FF + f2];
    const float cwdx1 = Wdx[(f2 + 1) * FF + (f2 + 1)];
    const float cbdx0 = bdx[f2];
    const float cbdx1 = bdx[f2 + 1];

    // ---- G1 mapping: column n = 16*w + col ----
    const int n1 = 16 * w + col;
    const float c_bdh = bdh[n1];

    // ---- G2/G3 mapping ----
    const int fw = (w & 7) * 16 + col;    // column for x_h (w<8) or alpha (w>=8)
    const float c_bh = bh[fw], c_bf = bf_[fw], c_bc = bc_[fw];

    // ---- G4 mapping: 4 N-tiles per wave ----
    float gb[4];
    #pragma unroll
    for (int e = 0; e < 4; ++e)
        gb[e] = bih[(4 * w + e) * 16 + col] + bhh[(4 * w + e) * 16 + col];

    // ---- G5 mapping: row = w, h-indices h4..h4+3 ----
    const int h4 = L * 4;
    float cst[4] = {0.f, 0.f, 0.f, 0.f};

    for (int i = tid; i < 16 * 264; i += 1024) h32[i] = 0.f;

    // prefetch t=0 inputs
    long inbase = ((long)(r0 + w) * TT + 0) * FF + f2;
    float2 px = *(const float2*)(values + inbase);
    float2 pm = *(const float2*)(mask + inbase);
    float2 pd = *(const float2*)(deltas + inbase);
    __syncthreads();

    for (int t = 0; t < TT; ++t) {
        // ================= IN: stage x,m,d; gamma_x; fill A-arrays =================
        {
            *(float2*)(x32 + w * 132 + f2) = px;
            *(float2*)(m32 + w * 132 + f2) = pm;
            float g0 = fexp(-fmaxf(pd.x * cwdx0 + cbdx0, 0.f));
            float g1 = fexp(-fmaxf(pd.y * cwdx1 + cbdx1, 0.f));
            *(uint32_t*)(dA + aidx(f2, w)) = pack2(pd.x, pd.y);
            *(uint32_t*)(gxmA + aidx(f2, w)) = pack2(g0, g1);
            uint32_t pmu = pack2(pm.x, pm.y);
            *(uint32_t*)(gxmA + aidx(128 + f2, w)) = pmu;
            *(uint32_t*)(actA + aidx(128 + f2, w)) = pmu;
        }
        __syncthreads();  // S1

        // ================= G1: gamma_h GEMM (1 col/wave) + decay h =================
        {
            f4v ac = {0.f, 0.f, 0.f, 0.f};
            #pragma unroll
            for (int kt = 0; kt < 4; ++kt) {
                s8v ad = *(const s8v*)(dA + kt * 512 + L * 8);
                s8v b = WDHB[(kt * 16 + w) * 64 + L];
                ac = __builtin_amdgcn_mfma_f32_16x16x32_bf16(ad, b, ac, 0, 0, 0);
            }
            #pragma unroll
            for (int r = 0; r < 4; ++r) {
                int m = q * 4 + r;
                float hd = h32[m * 264 + n1] * fexp(-fmaxf(ac[r] + c_bdh, 0.f));
                uint16_t hb = f2bf(hd);
                hA[aidx(n1, m)] = hb;
                actA[aidx(256 + n1, m)] = hb;
            }
        }
        __syncthreads();  // S2

        // ================= G2: x_h (waves 0-7) || alpha (waves 8-15) =================
        float xh[4], xr[4], mr[4], acc1 = 0.f;
        if (w < 8) {
            f4v a = {0.f, 0.f, 0.f, 0.f};
            #pragma unroll
            for (int kt = 0; kt < 8; ++kt) {
                s8v ah = *(const s8v*)(hA + kt * 512 + L * 8);
                s8v b = WHB[(kt * 8 + w) * 64 + L];
                a = __builtin_amdgcn_mfma_f32_16x16x32_bf16(ah, b, a, 0, 0, 0);
            }
            #pragma unroll
            for (int r = 0; r < 4; ++r) {
                int m = q * 4 + r;
                xh[r] = a[r] + c_bh;
                xr[r] = x32[m * 132 + fw];
                mr[r] = m32[m * 132 + fw];
                acc1 += fabsf(xh[r] - xr[r]) * mr[r];
                float xc = mr[r] * xr[r] + (1.f - mr[r]) * xh[r];
                xcA[aidx(fw, m)] = f2bf(xc);
            }
        } else {
            f4v a = {0.f, 0.f, 0.f, 0.f};
            #pragma unroll
            for (int kt = 0; kt < 8; ++kt) {
                s8v ag = *(const s8v*)(gxmA + kt * 512 + L * 8);
                s8v b = WCB[(kt * 8 + (w - 8)) * 64 + L];
                a = __builtin_amdgcn_mfma_f32_16x16x32_bf16(ag, b, a, 0, 0, 0);
            }
            #pragma unroll
            for (int r = 0; r < 4; ++r)
                al32[(q * 4 + r) * 136 + fw] = a[r] + c_bc;
        }
        __syncthreads();  // S3

        // ================= G3: z_h GEMM + combine (waves 0-7) =================
        if (w < 8) {
            f4v az = {0.f, 0.f, 0.f, 0.f};
            #pragma unroll
            for (int kt = 0; kt < 4; ++kt) {
                s8v axc = *(const s8v*)(xcA + kt * 512 + L * 8);
                s8v b = WFB[(kt * 8 + w) * 64 + L];
                az = __builtin_amdgcn_mfma_f32_16x16x32_bf16(axc, b, az, 0, 0, 0);
            }
            float acc2 = 0.f, acc3 = 0.f;
            #pragma unroll
            for (int r = 0; r < 4; ++r) {
                int m = q * 4 + r;
                float zh = az[r] + c_bf;
                float al = al32[m * 136 + fw];
                float ch = al * zh + (1.f - al) * xh[r];
                acc2 += fabsf(zh - xr[r]) * mr[r];
                acc3 += fabsf(ch - xr[r]) * mr[r];
                float cc = mr[r] * xr[r] + (1.f - mr[r]) * ch;
                out_imp[((long)(r0 + m) * TT + t) * FF + fw] = cc;
                actA[aidx(fw, m)] = f2bf(cc);
            }
            float a1 = acc1, a2 = acc2, a3 = acc3;
            for (int off = 32; off; off >>= 1) {
                a1 += __shfl_down(a1, off);
                a2 += __shfl_down(a2, off);
                a3 += __shfl_down(a3, off);
            }
            if (L == 0) { wred[0][w] = a1; wred[1][w] = a2; wred[2][w] = a3; }
        }
        __syncthreads();  // S4

        if (tid < 3) {
            float s = 0.f;
            #pragma unroll
            for (int e = 0; e < 8; ++e) s += wred[tid][e];
            part[((long)tid * TT + t) * NB + blk] = s;
        }
        // ================= G4: gates GEMM (K=512, 4 N-tiles/wave) =================
        {
            // prefetch next-step inputs while MFMAs run
            int tn = (t + 1 < TT) ? t + 1 : t;
            inbase = ((long)(r0 + w) * TT + tn) * FF + f2;
            px = *(const float2*)(values + inbase);
            pm = *(const float2*)(mask + inbase);
            pd = *(const float2*)(deltas + inbase);

            s8v aact[16];
            #pragma unroll
            for (int kt = 0; kt < 16; ++kt) aact[kt] = *(const s8v*)(actA + kt * 512 + L * 8);
            #pragma unroll
            for (int e = 0; e < 4; ++e) {
                f4v g = {0.f, 0.f, 0.f, 0.f};
                #pragma unroll
                for (int kt = 0; kt < 16; ++kt) {
                    s8v b = W2B[(kt * 64 + 4 * w + e) * 64 + L];
                    g = __builtin_amdgcn_mfma_f32_16x16x32_bf16(aact[kt], b, g, 0, 0, 0);
                }
                int gg = 4 * w + e;                 // global N-tile 0..63
                int gate = gg >> 4;                 // 0..3 (i,f,g,o)
                int hb = (gg & 15) * 16 + col;      // h index 0..255
                #pragma unroll
                for (int r = 0; r < 4; ++r)
                    g32[(q * 4 + r) * GPAD + hb * 4 + gate] = g[r] + gb[e];
            }
        }
        __syncthreads();  // S5

        // ================= G5: LSTM pointwise (row = w, 4 h/thread) =================
        {
            const float* gr = g32 + w * GPAD + h4 * 4;
            float* hr = h32 + w * 264 + h4;
            float hn[4];
            #pragma unroll
            for (int e = 0; e < 4; ++e) {
                float4 gv = *(const float4*)(gr + 4 * e);   // [i,f,g,o]
                cst[e] = fsigm(gv.y) * cst[e] + fsigm(gv.x) * ftanh(gv.z);
                hn[e] = fsigm(gv.w) * ftanh(cst[e]);
            }
            *(float4*)hr = make_float4(hn[0], hn[1], hn[2], hn[3]);
        }
        __syncthreads();  // S6
    }
}

// ---------------- finisher ----------------
__global__ void finisher(const float* __restrict__ part, const float* __restrict__ msum,
                         float* __restrict__ out2) {
    int t = threadIdx.x;
    float s1 = 0.f, s2 = 0.f, s3 = 0.f;
    const float* p1 = part + ((long)0 * TT + t) * NB;
    const float* p2 = part + ((long)1 * TT + t) * NB;
    const float* p3 = part + ((long)2 * TT + t) * NB;
    for (int b = 0; b < NB; ++b) { s1 += p1[b]; s2 += p2[b]; s3 += p3[b]; }
    float den = msum[t] + EPSL;
    float l12 = (s1 + s2) / den;
    float l3 = s3 / den;
    float xl = l12 + (float)(TT - t) * l3;
    float ml = l3;
    __shared__ float r1[4], r2[4];
    for (int off = 32; off; off >>= 1) {
        xl += __shfl_down(xl, off);
        ml += __shfl_down(ml, off);
    }
    if ((t & 63) == 0) { r1[t >> 6] = xl; r2[t >> 6] = ml; }
    __syncthreads();
    if (t == 0) {
        float X = r1[0] + r1[1] + r1[2] + r1[3];
        float M = r2[0] + r2[1] + r2[2] + r2[3];
        out2[0] = X / (float)(TT * 3);
        out2[1] = M / (float)TT;
    }
}

extern "C" void kernel_launch(void* const* d_in, const int* in_sizes, int n_in,
                              void* d_out, int out_size, void* d_ws, size_t ws_size,
                              hipStream_t stream) {
    const float* values = (const float*)d_in[0];
    const float* mask   = (const float*)d_in[1];
    const float* deltas = (const float*)d_in[2];
    const float* Wdh = (const float*)d_in[3];
    const float* bdh = (const float*)d_in[4];
    const float* Wdx = (const float*)d_in[5];
    const float* bdx = (const float*)d_in[6];
    const float* Wh  = (const float*)d_in[7];
    const float* bh  = (const float*)d_in[8];
    const float* Wf  = (const float*)d_in[9];
    const float* bf_ = (const float*)d_in[10];
    const float* Wc  = (const float*)d_in[11];
    const float* bc_ = (const float*)d_in[12];
    const float* Wih = (const float*)d_in[13];
    const float* Whh = (const float*)d_in[14];
    const float* bih = (const float*)d_in[15];
    const float* bhh = (const float*)d_in[16];

    float* out = (float*)d_out;
    uint16_t* wsu = (uint16_t*)d_ws;
    float* msum = (float*)((char*)d_ws + OFF_MSUM);
    float* part = (float*)((char*)d_ws + OFF_PART);

    prep_weights<<<2496, 256, 0, stream>>>(Wdh, Wh, Wf, Wc, Wih, Whh, wsu);
    msum_kernel<<<TT, 256, 0, stream>>>(mask, msum);
    rits_main<<<NB, 1024, 0, stream>>>(values, mask, deltas, bdh, Wdx, bdx,
                                       bh, bf_, bc_, bih, bhh, wsu, part, out);
    finisher<<<1, 256, 0, stream>>>(part, msum, out + (long)BB * TT * FF);
}